// Round 12
// baseline (255.656 us; speedup 1.0000x reference)
//
#include <hip/hip_runtime.h>
#include <hip/hip_bf16.h>

#define PB   256   // edge-stripe blocks for bucket_scatter (100k reservation atomics)
#define CAP  5120  // per-bucket capacity (Poisson(4096), sigma 64 -> 16 sigma slack)

typedef short bf16x8 __attribute__((ext_vector_type(8)));
typedef float f32x4  __attribute__((ext_vector_type(4)));

__device__ __forceinline__ unsigned short f2bf(float f) {  // RNE f32->bf16
    unsigned u = __float_as_uint(f);
    u += 0x7FFFu + ((u >> 16) & 1u);
    return (unsigned short)(u >> 16);
}

// ============ CSR build, pass 1: bucketize edges with atomic reservation ============
// Per block: LDS histogram of its stripe -> one global atomicAdd per bucket
// (rotated walk order to decorrelate hot lines across blocks) -> write
// pairs[b*CAP + slot] = src | dst_local<<20.
__global__ __launch_bounds__(256) void bucket_scatter(const int* __restrict__ src,
                                                      const int* __restrict__ dst,
                                                      int* __restrict__ gcount,
                                                      int* __restrict__ pairs,
                                                      int E, int NB) {
    __shared__ int h[512];
    const int tid = threadIdx.x;
    for (int i = tid; i < NB; i += 256) h[i] = 0;
    __syncthreads();
    const int per = (E + PB - 1) / PB;
    const int s = blockIdx.x * per;
    const int e = min(E, s + per);
    for (int i = s + tid; i < e; i += 256) atomicAdd(&h[dst[i] >> 8], 1);
    __syncthreads();
    // rotated reservation walk: block k starts at offset 3k -> different lines
    for (int i = tid; i < NB; i += 256) {
        int b = i + (blockIdx.x & 127) * 3;          // max 390+381=771
        if (b >= NB) b -= NB;                        // single wrap suffices
        const int c = h[b];
        h[b] = (c > 0) ? atomicAdd(&gcount[b], c) : 0;
    }
    __syncthreads();
    for (int i = s + tid; i < e; i += 256) {
        const int d = dst[i];
        const int b = d >> 8;
        const int slot = atomicAdd(&h[b], 1);        // bucket-local slot
        if (slot < CAP)
            pairs[(size_t)b * CAP + slot] = src[i] | ((d & 255) << 20);
    }
}

// ============ CSR build, pass 2: per-bucket finalize (single global read via LDS) =====
__global__ __launch_bounds__(256) void csr_finalize(const int* __restrict__ pairs,
                                                    const int* __restrict__ gcount,
                                                    int2* __restrict__ rowrange,
                                                    int* __restrict__ col, int N) {
    __shared__ int sp[CAP];
    __shared__ int h[256];
    __shared__ int tmp[256];
    __shared__ int cur[256];
    const int tid = threadIdx.x;
    const int b = blockIdx.x;
    const size_t base = (size_t)b * CAP;
    const int cnt = min(gcount[b], (int)CAP);

    for (int i = tid; i < cnt; i += 256) sp[i] = pairs[base + i];
    h[tid] = 0;
    __syncthreads();
    for (int i = tid; i < cnt; i += 256)
        atomicAdd(&h[(sp[i] >> 20) & 255], 1);
    __syncthreads();
    const int v = h[tid];
    tmp[tid] = v;
    __syncthreads();
    for (int off = 1; off < 256; off <<= 1) {
        int t = (tid >= off) ? tmp[tid - off] : 0;
        __syncthreads();
        tmp[tid] += t;
        __syncthreads();
    }
    const int excl = tmp[tid] - v;
    const int node = (b << 8) + tid;
    if (node < N) rowrange[node] = make_int2((int)base + excl, (int)base + excl + v);
    cur[tid] = excl;
    __syncthreads();
    for (int i = tid; i < cnt; i += 256) {
        const int p = sp[i];
        const int slot = atomicAdd(&cur[(p >> 20) & 255], 1);
        col[base + slot] = p & 0xFFFFF;
    }
}

// ============ prep: weight packs + bf16 shadow of x + gcount zeroing, one launch ======
// blocks 0..95: pack bw per MFMA B-frag swizzle
//   bw[((s*4+t)*64 + lane)*8 + j] = B[s*32 + (lane>>4)*8 + j][t*16 + (lane&15)]
// blocks 96.. : f32 -> bf16 copy of x (8 elems/thread); first NB threads also
//              zero gcount (replaces a hipMemsetAsync launch).
__global__ __launch_bounds__(256) void prep_kernel(
        const float* __restrict__ x, unsigned short* __restrict__ xb, int n8,
        const float* __restrict__ Ws1, const float* __restrict__ Wn1,
        const float* __restrict__ Ws2, const float* __restrict__ Wn2,
        const float* __restrict__ Ws3, const float* __restrict__ Wn3,
        unsigned short* __restrict__ bw,
        int* __restrict__ gcount, int NB) {
    if (blockIdx.x < 96) {
        const int i = blockIdx.x * 256 + threadIdx.x;  // 0..24575
        const int w = i >> 13;
        const int r = i & 8191;
        const float* Ws = (w == 0) ? Ws1 : (w == 1) ? Ws2 : Ws3;
        const float* Wn = (w == 0) ? Wn1 : (w == 1) ? Wn2 : Wn3;
        const int j = r & 7;
        const int L = (r >> 3) & 63;
        const int t = (r >> 9) & 3;
        const int s = r >> 11;
        const int k = s * 32 + ((L >> 4) << 3) + j;
        const int n = t * 16 + (L & 15);
        const float v = (k < 64) ? Ws[k * 64 + n] : Wn[(k - 64) * 64 + n];
        bw[i] = f2bf(v);
    } else {
        const int g = (blockIdx.x - 96) * 256 + threadIdx.x;
        if (g < NB) gcount[g] = 0;
        if (g >= n8) return;
        const float4 v0 = *(const float4*)(x + (size_t)g * 8);
        const float4 v1 = *(const float4*)(x + (size_t)g * 8 + 4);
        uint4 o;
        o.x = (unsigned)f2bf(v0.x) | ((unsigned)f2bf(v0.y) << 16);
        o.y = (unsigned)f2bf(v0.z) | ((unsigned)f2bf(v0.w) << 16);
        o.z = (unsigned)f2bf(v1.x) | ((unsigned)f2bf(v1.y) << 16);
        o.w = (unsigned)f2bf(v1.z) | ((unsigned)f2bf(v1.w) << 16);
        *(uint4*)(xb + (size_t)g * 8) = o;
    }
}

// ============ fused layer: gather-mean (high-MLP) + MFMA update ============
// 32 nodes/block, 128 threads (2 waves). Unchanged from R10 (control).
#define ACC8U(A, V)                                                   \
    A[0] += __uint_as_float((V).x << 16);                             \
    A[1] += __uint_as_float((V).x & 0xFFFF0000u);                     \
    A[2] += __uint_as_float((V).y << 16);                             \
    A[3] += __uint_as_float((V).y & 0xFFFF0000u);                     \
    A[4] += __uint_as_float((V).z << 16);                             \
    A[5] += __uint_as_float((V).z & 0xFFFF0000u);                     \
    A[6] += __uint_as_float((V).w << 16);                             \
    A[7] += __uint_as_float((V).w & 0xFFFF0000u);

__global__ __launch_bounds__(128) void sage_fused_kernel(
        const unsigned short* __restrict__ xin, const int* __restrict__ col,
        const int2* __restrict__ rowrange,
        const unsigned short* __restrict__ bswp, const float* __restrict__ bias,
        unsigned short* __restrict__ outb,   // may be null; must not alias xin
        float* __restrict__ outf,            // may be null
        int N, int do_relu) {
    __shared__ __align__(16) unsigned short smean[32][72];

    const int tid = threadIdx.x;
    const int node0 = blockIdx.x * 32;
    const int lane = tid & 63;

    // ---- phase 1: gather mean for node (tid>>2), 32 B per lane ----
    {
        const int nl = tid >> 2;             // 0..31
        const int node = node0 + nl;
        const int c16 = (tid & 3) * 16;      // short offset: 0,16,32,48
        float accA[8] = {0.f}, accB[8] = {0.f};
        float accC[8] = {0.f}, accD[8] = {0.f};
        float rd = 0.f;
        if (node < N) {
            const int2 rr = rowrange[node];
            const int beg = rr.x;
            const int end = rr.y;
            int i = beg;
            for (; i + 4 <= end; i += 4) {
                const int s0 = col[i + 0];
                const int s1 = col[i + 1];
                const int s2 = col[i + 2];
                const int s3 = col[i + 3];
                const unsigned short* p0 = xin + (size_t)s0 * 64 + c16;
                const unsigned short* p1 = xin + (size_t)s1 * 64 + c16;
                const unsigned short* p2 = xin + (size_t)s2 * 64 + c16;
                const unsigned short* p3 = xin + (size_t)s3 * 64 + c16;
                const uint4 a0 = *(const uint4*)(p0);
                const uint4 b0 = *(const uint4*)(p0 + 8);
                const uint4 a1 = *(const uint4*)(p1);
                const uint4 b1 = *(const uint4*)(p1 + 8);
                const uint4 a2 = *(const uint4*)(p2);
                const uint4 b2 = *(const uint4*)(p2 + 8);
                const uint4 a3 = *(const uint4*)(p3);
                const uint4 b3 = *(const uint4*)(p3 + 8);
                ACC8U(accA, a0) ACC8U(accB, b0)
                ACC8U(accC, a1) ACC8U(accD, b1)
                ACC8U(accA, a2) ACC8U(accB, b2)
                ACC8U(accC, a3) ACC8U(accD, b3)
            }
            for (; i < end; ++i) {
                const unsigned short* p = xin + (size_t)col[i] * 64 + c16;
                const uint4 a = *(const uint4*)(p);
                const uint4 b = *(const uint4*)(p + 8);
                ACC8U(accA, a) ACC8U(accB, b)
            }
            rd = 1.0f / fmaxf((float)(end - beg), 1.0f);
        }
        uint4 o0, o1;
        {
            float m[8];
#pragma unroll
            for (int k = 0; k < 8; ++k) m[k] = (accA[k] + accC[k]) * rd;
            o0.x = (unsigned)f2bf(m[0]) | ((unsigned)f2bf(m[1]) << 16);
            o0.y = (unsigned)f2bf(m[2]) | ((unsigned)f2bf(m[3]) << 16);
            o0.z = (unsigned)f2bf(m[4]) | ((unsigned)f2bf(m[5]) << 16);
            o0.w = (unsigned)f2bf(m[6]) | ((unsigned)f2bf(m[7]) << 16);
#pragma unroll
            for (int k = 0; k < 8; ++k) m[k] = (accB[k] + accD[k]) * rd;
            o1.x = (unsigned)f2bf(m[0]) | ((unsigned)f2bf(m[1]) << 16);
            o1.y = (unsigned)f2bf(m[2]) | ((unsigned)f2bf(m[3]) << 16);
            o1.z = (unsigned)f2bf(m[4]) | ((unsigned)f2bf(m[5]) << 16);
            o1.w = (unsigned)f2bf(m[6]) | ((unsigned)f2bf(m[7]) << 16);
        }
        *(uint4*)(&smean[nl][c16])     = o0;
        *(uint4*)(&smean[nl][c16 + 8]) = o1;
    }
    __syncthreads();

    // ---- phase 2: MFMA update (2 waves x 16 nodes) ----
    const int wave = tid >> 6;
    const int m    = lane & 15;
    const int quad = lane >> 4;
    const int nw0  = node0 + wave * 16;

    int arow = nw0 + m;
    if (arow >= N) arow = N - 1;             // clamp; stores are guarded
    const unsigned short* xr = xin + (size_t)arow * 64 + quad * 8;

    f32x4 acc[4];
#pragma unroll
    for (int t = 0; t < 4; ++t) {
        const float b = bias[t * 16 + m];
        acc[t] = (f32x4){b, b, b, b};
    }

#pragma unroll
    for (int s = 0; s < 4; ++s) {
        bf16x8 a;
        if (s < 2) a = *(const bf16x8*)(xr + s * 32);
        else       a = *(const bf16x8*)(&smean[wave * 16 + m][(s - 2) * 32 + quad * 8]);
#pragma unroll
        for (int t = 0; t < 4; ++t) {
            const bf16x8 bf = *(const bf16x8*)(bswp + (((s * 4 + t) * 64 + lane) << 3));
            acc[t] = __builtin_amdgcn_mfma_f32_16x16x32_bf16(a, bf, acc[t], 0, 0, 0);
        }
    }

    // C/D: col = t*16 + m, row(node) = nw0 + quad*4 + r
#pragma unroll
    for (int t = 0; t < 4; ++t) {
        const int colg = t * 16 + m;
#pragma unroll
        for (int r = 0; r < 4; ++r) {
            const int node = nw0 + quad * 4 + r;
            if (node < N) {
                float v = acc[t][r];
                if (do_relu) v = fmaxf(v, 0.f);
                if (outf) outf[(size_t)node * 64 + colg] = v;
                if (outb) outb[(size_t)node * 64 + colg] = f2bf(v);
            }
        }
    }
}

extern "C" void kernel_launch(void* const* d_in, const int* in_sizes, int n_in,
                              void* d_out, int out_size, void* d_ws, size_t ws_size,
                              hipStream_t stream) {
    const float* x   = (const float*)d_in[0];
    const int*   ei  = (const int*)d_in[1];
    const float* ws1 = (const float*)d_in[2];
    const float* wn1 = (const float*)d_in[3];
    const float* b1  = (const float*)d_in[4];
    const float* ws2 = (const float*)d_in[5];
    const float* wn2 = (const float*)d_in[6];
    const float* b2  = (const float*)d_in[7];
    const float* ws3 = (const float*)d_in[8];
    const float* wn3 = (const float*)d_in[9];
    const float* b3  = (const float*)d_in[10];

    const int N = in_sizes[0] / 64;   // 100000
    const int E = in_sizes[1] / 2;    // 1600000
    const int* src = ei;
    const int* dst = ei + E;
    const int NB = (N + 255) >> 8;    // 391 buckets

    float* out = (float*)d_out;

    auto align256 = [](size_t v) { return (v + 255) / 256 * 256; };
    char* p = (char*)d_ws;
    int*  gcount   = (int*)p;  p += align256((size_t)NB * 4);
    int*  pairs    = (int*)p;  p += align256((size_t)NB * CAP * 4);
    int*  col      = (int*)p;  p += align256((size_t)NB * CAP * 4);
    int2* rowrange = (int2*)p; p += align256((size_t)N * 8);
    unsigned short* xb  = (unsigned short*)p; p += align256((size_t)N * 64 * 2);
    unsigned short* xb2 = (unsigned short*)p; p += align256((size_t)N * 64 * 2);
    unsigned short* bw  = (unsigned short*)p; p += align256(3 * 8192 * 2);

    const int n8 = N * 64 / 8;                      // 800000
    const int prep_blocks = 96 + (n8 + 255) / 256;  // 96 + 3125
    const int fused_blocks = (N + 31) / 32;         // 3125

    // ---- prep first: packs weights, converts x, zeroes gcount ----
    prep_kernel<<<prep_blocks, 256, 0, stream>>>(x, xb, n8, ws1, wn1, ws2, wn2,
                                                 ws3, wn3, bw, gcount, NB);

    // ---- CSR build: 2 kernels (atomic bucket reservation, gapped storage) ----
    bucket_scatter<<<PB, 256, 0, stream>>>(src, dst, gcount, pairs, E, NB);
    csr_finalize  <<<NB, 256, 0, stream>>>(pairs, gcount, rowrange, col, N);

    // ---- 3 fused layers (ping-pong xb <-> xb2) ----
    sage_fused_kernel<<<fused_blocks, 128, 0, stream>>>(xb,  col, rowrange, bw,         b1, xb2,     nullptr, N, 1);
    sage_fused_kernel<<<fused_blocks, 128, 0, stream>>>(xb2, col, rowrange, bw + 8192,  b2, xb,      nullptr, N, 1);
    sage_fused_kernel<<<fused_blocks, 128, 0, stream>>>(xb,  col, rowrange, bw + 16384, b3, nullptr, out,     N, 0);
}

// Round 13
// 255.198 us; speedup vs baseline: 1.0018x; 1.0018x over previous
//
#include <hip/hip_runtime.h>
#include <hip/hip_bf16.h>

#define PB   512   // edge-stripe blocks inside build_kernel (2 blocks/CU)
#define WPB  96    // weight-pack blocks
#define CAP  5120  // per-bucket capacity (Poisson(4096), sigma 64 -> 16 sigma slack)

typedef short bf16x8 __attribute__((ext_vector_type(8)));
typedef float f32x4  __attribute__((ext_vector_type(4)));

__device__ __forceinline__ unsigned short f2bf(float f) {  // RNE f32->bf16
    unsigned u = __float_as_uint(f);
    u += 0x7FFFu + ((u >> 16) & 1u);
    return (unsigned short)(u >> 16);
}

// ============ build: bucketize edges + pack weights + bf16-convert x, ONE kernel ======
// blocks 0..PB-1        : edge-stripe bucketize (LDS hist -> rotated atomic
//                         reservation in gcount -> pairs[b*CAP+slot])
// blocks PB..PB+WPB-1   : pack bw per MFMA B-frag swizzle
//   bw[((s*4+t)*64+lane)*8+j] = B[s*32+(lane>>4)*8+j][t*16+(lane&15)]
// blocks PB+WPB..       : f32 -> bf16 copy of x (8 elems/thread)
// Heterogeneous blocks co-reside: streaming conversion hides the scatter's
// atomic/latency stalls. gcount must be zeroed BEFORE this kernel.
__global__ __launch_bounds__(256) void build_kernel(
        const int* __restrict__ src, const int* __restrict__ dst,
        int* __restrict__ gcount, int* __restrict__ pairs, int E, int NB,
        const float* __restrict__ x, unsigned short* __restrict__ xb, int n8,
        const float* __restrict__ Ws1, const float* __restrict__ Wn1,
        const float* __restrict__ Ws2, const float* __restrict__ Wn2,
        const float* __restrict__ Ws3, const float* __restrict__ Wn3,
        unsigned short* __restrict__ bw) {
    __shared__ int h[512];
    const int tid = threadIdx.x;

    if (blockIdx.x < PB) {
        // ---- bucketize stripe ----
        for (int i = tid; i < NB; i += 256) h[i] = 0;
        __syncthreads();
        const int per = (E + PB - 1) / PB;
        const int s = blockIdx.x * per;
        const int e = min(E, s + per);
        for (int i = s + tid; i < e; i += 256) atomicAdd(&h[dst[i] >> 8], 1);
        __syncthreads();
        // rotated reservation walk: decorrelate hot gcount lines across blocks
        for (int i = tid; i < NB; i += 256) {
            int b = i + (blockIdx.x & 127) * 3;
            if (b >= NB) b -= NB;
            const int c = h[b];
            h[b] = (c > 0) ? atomicAdd(&gcount[b], c) : 0;
        }
        __syncthreads();
        for (int i = s + tid; i < e; i += 256) {
            const int d = dst[i];
            const int b = d >> 8;
            const int slot = atomicAdd(&h[b], 1);
            if (slot < CAP)
                pairs[(size_t)b * CAP + slot] = src[i] | ((d & 255) << 20);
        }
    } else if (blockIdx.x < PB + WPB) {
        // ---- weight pack ----
        const int i = (blockIdx.x - PB) * 256 + tid;   // 0..24575
        const int w = i >> 13;
        const int r = i & 8191;
        const float* Ws = (w == 0) ? Ws1 : (w == 1) ? Ws2 : Ws3;
        const float* Wn = (w == 0) ? Wn1 : (w == 1) ? Wn2 : Wn3;
        const int j = r & 7;
        const int L = (r >> 3) & 63;
        const int t = (r >> 9) & 3;
        const int s = r >> 11;
        const int k = s * 32 + ((L >> 4) << 3) + j;
        const int n = t * 16 + (L & 15);
        const float v = (k < 64) ? Ws[k * 64 + n] : Wn[(k - 64) * 64 + n];
        bw[i] = f2bf(v);
    } else {
        // ---- f32 -> bf16 shadow of x ----
        const int g = (blockIdx.x - PB - WPB) * 256 + tid;
        if (g >= n8) return;
        const float4 v0 = *(const float4*)(x + (size_t)g * 8);
        const float4 v1 = *(const float4*)(x + (size_t)g * 8 + 4);
        uint4 o;
        o.x = (unsigned)f2bf(v0.x) | ((unsigned)f2bf(v0.y) << 16);
        o.y = (unsigned)f2bf(v0.z) | ((unsigned)f2bf(v0.w) << 16);
        o.z = (unsigned)f2bf(v1.x) | ((unsigned)f2bf(v1.y) << 16);
        o.w = (unsigned)f2bf(v1.z) | ((unsigned)f2bf(v1.w) << 16);
        *(uint4*)(xb + (size_t)g * 8) = o;
    }
}

// ============ CSR build, pass 2: per-bucket finalize (single global read via LDS) =====
__global__ __launch_bounds__(256) void csr_finalize(const int* __restrict__ pairs,
                                                    const int* __restrict__ gcount,
                                                    int2* __restrict__ rowrange,
                                                    int* __restrict__ col, int N) {
    __shared__ int sp[CAP];
    __shared__ int h[256];
    __shared__ int tmp[256];
    __shared__ int cur[256];
    const int tid = threadIdx.x;
    const int b = blockIdx.x;
    const size_t base = (size_t)b * CAP;
    const int cnt = min(gcount[b], (int)CAP);

    for (int i = tid; i < cnt; i += 256) sp[i] = pairs[base + i];
    h[tid] = 0;
    __syncthreads();
    for (int i = tid; i < cnt; i += 256)
        atomicAdd(&h[(sp[i] >> 20) & 255], 1);
    __syncthreads();
    const int v = h[tid];
    tmp[tid] = v;
    __syncthreads();
    for (int off = 1; off < 256; off <<= 1) {
        int t = (tid >= off) ? tmp[tid - off] : 0;
        __syncthreads();
        tmp[tid] += t;
        __syncthreads();
    }
    const int excl = tmp[tid] - v;
    const int node = (b << 8) + tid;
    if (node < N) rowrange[node] = make_int2((int)base + excl, (int)base + excl + v);
    cur[tid] = excl;
    __syncthreads();
    for (int i = tid; i < cnt; i += 256) {
        const int p = sp[i];
        const int slot = atomicAdd(&cur[(p >> 20) & 255], 1);
        col[base + slot] = p & 0xFFFFF;
    }
}

// ============ fused layer: gather-mean (high-MLP) + MFMA update ============
// 32 nodes/block, 128 threads (2 waves). Unchanged (control).
#define ACC8U(A, V)                                                   \
    A[0] += __uint_as_float((V).x << 16);                             \
    A[1] += __uint_as_float((V).x & 0xFFFF0000u);                     \
    A[2] += __uint_as_float((V).y << 16);                             \
    A[3] += __uint_as_float((V).y & 0xFFFF0000u);                     \
    A[4] += __uint_as_float((V).z << 16);                             \
    A[5] += __uint_as_float((V).z & 0xFFFF0000u);                     \
    A[6] += __uint_as_float((V).w << 16);                             \
    A[7] += __uint_as_float((V).w & 0xFFFF0000u);

__global__ __launch_bounds__(128) void sage_fused_kernel(
        const unsigned short* __restrict__ xin, const int* __restrict__ col,
        const int2* __restrict__ rowrange,
        const unsigned short* __restrict__ bswp, const float* __restrict__ bias,
        unsigned short* __restrict__ outb,   // may be null; must not alias xin
        float* __restrict__ outf,            // may be null
        int N, int do_relu) {
    __shared__ __align__(16) unsigned short smean[32][72];

    const int tid = threadIdx.x;
    const int node0 = blockIdx.x * 32;
    const int lane = tid & 63;

    // ---- phase 1: gather mean for node (tid>>2), 32 B per lane ----
    {
        const int nl = tid >> 2;             // 0..31
        const int node = node0 + nl;
        const int c16 = (tid & 3) * 16;      // short offset: 0,16,32,48
        float accA[8] = {0.f}, accB[8] = {0.f};
        float accC[8] = {0.f}, accD[8] = {0.f};
        float rd = 0.f;
        if (node < N) {
            const int2 rr = rowrange[node];
            const int beg = rr.x;
            const int end = rr.y;
            int i = beg;
            for (; i + 4 <= end; i += 4) {
                const int s0 = col[i + 0];
                const int s1 = col[i + 1];
                const int s2 = col[i + 2];
                const int s3 = col[i + 3];
                const unsigned short* p0 = xin + (size_t)s0 * 64 + c16;
                const unsigned short* p1 = xin + (size_t)s1 * 64 + c16;
                const unsigned short* p2 = xin + (size_t)s2 * 64 + c16;
                const unsigned short* p3 = xin + (size_t)s3 * 64 + c16;
                const uint4 a0 = *(const uint4*)(p0);
                const uint4 b0 = *(const uint4*)(p0 + 8);
                const uint4 a1 = *(const uint4*)(p1);
                const uint4 b1 = *(const uint4*)(p1 + 8);
                const uint4 a2 = *(const uint4*)(p2);
                const uint4 b2 = *(const uint4*)(p2 + 8);
                const uint4 a3 = *(const uint4*)(p3);
                const uint4 b3 = *(const uint4*)(p3 + 8);
                ACC8U(accA, a0) ACC8U(accB, b0)
                ACC8U(accC, a1) ACC8U(accD, b1)
                ACC8U(accA, a2) ACC8U(accB, b2)
                ACC8U(accC, a3) ACC8U(accD, b3)
            }
            for (; i < end; ++i) {
                const unsigned short* p = xin + (size_t)col[i] * 64 + c16;
                const uint4 a = *(const uint4*)(p);
                const uint4 b = *(const uint4*)(p + 8);
                ACC8U(accA, a) ACC8U(accB, b)
            }
            rd = 1.0f / fmaxf((float)(end - beg), 1.0f);
        }
        uint4 o0, o1;
        {
            float m[8];
#pragma unroll
            for (int k = 0; k < 8; ++k) m[k] = (accA[k] + accC[k]) * rd;
            o0.x = (unsigned)f2bf(m[0]) | ((unsigned)f2bf(m[1]) << 16);
            o0.y = (unsigned)f2bf(m[2]) | ((unsigned)f2bf(m[3]) << 16);
            o0.z = (unsigned)f2bf(m[4]) | ((unsigned)f2bf(m[5]) << 16);
            o0.w = (unsigned)f2bf(m[6]) | ((unsigned)f2bf(m[7]) << 16);
#pragma unroll
            for (int k = 0; k < 8; ++k) m[k] = (accB[k] + accD[k]) * rd;
            o1.x = (unsigned)f2bf(m[0]) | ((unsigned)f2bf(m[1]) << 16);
            o1.y = (unsigned)f2bf(m[2]) | ((unsigned)f2bf(m[3]) << 16);
            o1.z = (unsigned)f2bf(m[4]) | ((unsigned)f2bf(m[5]) << 16);
            o1.w = (unsigned)f2bf(m[6]) | ((unsigned)f2bf(m[7]) << 16);
        }
        *(uint4*)(&smean[nl][c16])     = o0;
        *(uint4*)(&smean[nl][c16 + 8]) = o1;
    }
    __syncthreads();

    // ---- phase 2: MFMA update (2 waves x 16 nodes) ----
    const int wave = tid >> 6;
    const int m    = lane & 15;
    const int quad = lane >> 4;
    const int nw0  = node0 + wave * 16;

    int arow = nw0 + m;
    if (arow >= N) arow = N - 1;             // clamp; stores are guarded
    const unsigned short* xr = xin + (size_t)arow * 64 + quad * 8;

    f32x4 acc[4];
#pragma unroll
    for (int t = 0; t < 4; ++t) {
        const float b = bias[t * 16 + m];
        acc[t] = (f32x4){b, b, b, b};
    }

#pragma unroll
    for (int s = 0; s < 4; ++s) {
        bf16x8 a;
        if (s < 2) a = *(const bf16x8*)(xr + s * 32);
        else       a = *(const bf16x8*)(&smean[wave * 16 + m][(s - 2) * 32 + quad * 8]);
#pragma unroll
        for (int t = 0; t < 4; ++t) {
            const bf16x8 bf = *(const bf16x8*)(bswp + (((s * 4 + t) * 64 + lane) << 3));
            acc[t] = __builtin_amdgcn_mfma_f32_16x16x32_bf16(a, bf, acc[t], 0, 0, 0);
        }
    }

    // C/D: col = t*16 + m, row(node) = nw0 + quad*4 + r
#pragma unroll
    for (int t = 0; t < 4; ++t) {
        const int colg = t * 16 + m;
#pragma unroll
        for (int r = 0; r < 4; ++r) {
            const int node = nw0 + quad * 4 + r;
            if (node < N) {
                float v = acc[t][r];
                if (do_relu) v = fmaxf(v, 0.f);
                if (outf) outf[(size_t)node * 64 + colg] = v;
                if (outb) outb[(size_t)node * 64 + colg] = f2bf(v);
            }
        }
    }
}

extern "C" void kernel_launch(void* const* d_in, const int* in_sizes, int n_in,
                              void* d_out, int out_size, void* d_ws, size_t ws_size,
                              hipStream_t stream) {
    const float* x   = (const float*)d_in[0];
    const int*   ei  = (const int*)d_in[1];
    const float* ws1 = (const float*)d_in[2];
    const float* wn1 = (const float*)d_in[3];
    const float* b1  = (const float*)d_in[4];
    const float* ws2 = (const float*)d_in[5];
    const float* wn2 = (const float*)d_in[6];
    const float* b2  = (const float*)d_in[7];
    const float* ws3 = (const float*)d_in[8];
    const float* wn3 = (const float*)d_in[9];
    const float* b3  = (const float*)d_in[10];

    const int N = in_sizes[0] / 64;   // 100000
    const int E = in_sizes[1] / 2;    // 1600000
    const int* src = ei;
    const int* dst = ei + E;
    const int NB = (N + 255) >> 8;    // 391 buckets

    float* out = (float*)d_out;

    auto align256 = [](size_t v) { return (v + 255) / 256 * 256; };
    char* p = (char*)d_ws;
    int*  gcount   = (int*)p;  p += align256((size_t)NB * 4);
    int*  pairs    = (int*)p;  p += align256((size_t)NB * CAP * 4);
    int*  col      = (int*)p;  p += align256((size_t)NB * CAP * 4);
    int2* rowrange = (int2*)p; p += align256((size_t)N * 8);
    unsigned short* xb  = (unsigned short*)p; p += align256((size_t)N * 64 * 2);
    unsigned short* xb2 = (unsigned short*)p; p += align256((size_t)N * 64 * 2);
    unsigned short* bw  = (unsigned short*)p; p += align256(3 * 8192 * 2);

    const int n8 = N * 64 / 8;                             // 800000
    const int build_blocks = PB + WPB + (n8 + 255) / 256;  // 512 + 96 + 3125
    const int fused_blocks = (N + 31) / 32;                // 3125

    // ---- build: bucketize + weight pack + bf16 convert, one kernel ----
    hipMemsetAsync(gcount, 0, (size_t)NB * 4, stream);
    build_kernel<<<build_blocks, 256, 0, stream>>>(src, dst, gcount, pairs, E, NB,
                                                   x, xb, n8, ws1, wn1, ws2, wn2,
                                                   ws3, wn3, bw);
    csr_finalize<<<NB, 256, 0, stream>>>(pairs, gcount, rowrange, col, N);

    // ---- 3 fused layers (ping-pong xb <-> xb2) ----
    sage_fused_kernel<<<fused_blocks, 128, 0, stream>>>(xb,  col, rowrange, bw,         b1, xb2,     nullptr, N, 1);
    sage_fused_kernel<<<fused_blocks, 128, 0, stream>>>(xb2, col, rowrange, bw + 8192,  b2, xb,      nullptr, N, 1);
    sage_fused_kernel<<<fused_blocks, 128, 0, stream>>>(xb,  col, rowrange, bw + 16384, b3, nullptr, out,     N, 0);
}